// Round 8
// baseline (133.232 us; speedup 1.0000x reference)
//
#include <hip/hip_runtime.h>
#include <cmath>

#define BN 2
#define AN 3
#define SN 8
#define CN 20
#define IMGN 256
#define NSTEP 384   // A*S*S*B steps in scan order (k,i,j,b)
#define PRED_C 26   // 6 + C
#define NE (NSTEP * 6)
#define NBB 256          // kB blocks (2 row-units each)
#define NSB (NSTEP / BN) // 192 steps per batch
#define NRB 36           // kR blocks (NE/64)

__device__ __forceinline__ float wredf(float v){
  #pragma unroll
  for (int o = 32; o; o >>= 1) v += __shfl_xor(v, o);
  return v;
}
__device__ __forceinline__ double wredd(double v){
  #pragma unroll
  for (int o = 32; o; o >>= 1) v += __shfl_xor(v, o);
  return v;
}
// rocPRIM-style gfx9 DPP wave sum: result valid in lane 63. Pure VALU, no LDS pipe.
// (correctness HW-verified: rounds 4-7 absmax 0.0)
__device__ __forceinline__ float wsum_dpp(float x){
  x += __int_as_float(__builtin_amdgcn_update_dpp(0, __float_as_int(x), 0x111, 0xf, 0xf, false)); // row_shr:1
  x += __int_as_float(__builtin_amdgcn_update_dpp(0, __float_as_int(x), 0x112, 0xf, 0xf, false)); // row_shr:2
  x += __int_as_float(__builtin_amdgcn_update_dpp(0, __float_as_int(x), 0x114, 0xf, 0xf, false)); // row_shr:4
  x += __int_as_float(__builtin_amdgcn_update_dpp(0, __float_as_int(x), 0x118, 0xf, 0xf, false)); // row_shr:8
  x += __int_as_float(__builtin_amdgcn_update_dpp(0, __float_as_int(x), 0x142, 0xa, 0xf, false)); // row_bcast:15
  x += __int_as_float(__builtin_amdgcn_update_dpp(0, __float_as_int(x), 0x143, 0xc, 0xf, false)); // row_bcast:31
  return x;
}
__device__ __forceinline__ int finitef(float x){
  return (__float_as_uint(x) & 0x7f800000u) != 0x7f800000u;
}
// exact replica of reference _axis_mask index computation (f32 trunc + negative wrap)
__device__ __forceinline__ unsigned axism(float lo, float hi){
  float lof = truncf(fminf(fmaxf(lo, -1e9f), 1e9f));
  float hif = truncf(fminf(fmaxf(hi, -1e9f), 1e9f));
  int l = (int)lof, h = (int)hif;
  l = (l < 0) ? max(IMGN + l, 0) : min(l, IMGN);
  h = (h < 0) ? max(IMGN + h, 0) : min(h, IMGN);
  return (unsigned)l | ((unsigned)h << 16);
}

// per-step scan parameters; scan order t = ((k*S + i)*S + j)*B + b
__device__ __forceinline__ void step_params(int t, const float* __restrict__ pred,
                                            const float* __restrict__ anc,
                                            unsigned* valid, float* lv,
                                            unsigned* fx, unsigned* fy,
                                            unsigned* sx, unsigned* sy){
  int b = t % BN;
  int j = (t / BN) % SN;
  int i = (t / (BN * SN)) % SN;
  int k = t / (BN * SN * SN);
  const float* pc = pred + (size_t)((((b * AN + k) * SN + i) * SN + j)) * PRED_C;
  float x = pc[1], y = pc[2], wv = pc[3], hv = pc[4], v = pc[5];
  float aw = anc[2 * k], ah = anc[2 * k + 1];
  // xy gets sigmoid applied (k+2) times total (1 before loop + k+1 in loop)
  for (int m = 0; m < k + 2; ++m) {
    x = 1.0f / (1.0f + expf(-x));
    y = 1.0f / (1.0f + expf(-y));
  }
  // wh: (k+1) iterations of exp(.)*anchor[k], in f32 (overflow -> inf -> invalid)
  for (int m = 0; m < k + 1; ++m) {
    wv = expf(wv) * aw;
    hv = expf(hv) * ah;
  }
  float cx = (x + (float)j) / 8.0f * 256.0f;
  float cy = (y + (float)i) / 8.0f * 256.0f;
  float w  = wv / 8.0f * 256.0f;
  float h  = hv / 8.0f * 256.0f;
  *valid = (w > 0.0f) && (h > 0.0f) && finitef(w) && finitef(h);
  *lv = logf(fmaxf(1.0f, v));
  // NOTE reference quirk: x-mask (from cx,w) indexes dp's ROW axis, y-mask the COL axis
  *fx = axism(cx - w / 2.0f, cx + w / 2.0f);
  *fy = axism(cy - h / 2.0f, cy + h / 2.0f);
  *sx = axism(cx - w / 4.0f, cx + w / 4.0f);
  *sy = axism(cy - h / 4.0f, cy + h / 4.0f);
}

// ---------------- Kernel B: per-pixel step scan -> per-block per-step delta partials ----------------
// 256 blocks x 512 threads; 2 row-units per block (waves 0-3 -> ru0, waves 4-7 -> ru1,
// both same batch b). Per-WAVE compacted SELF-CONTAINED 16B entries {fy, sy, lv, t|flags}
// -> inner loop is ONE idx-affine ds_read_b128 (pipelined, no dependent LDS chain).
// Sink = per-block LDS accumulator; one coalesced 9216 B scratch write per block.
__global__ __launch_bounds__(512) void yolo_kB(const float* __restrict__ pred,
                                               const float* __restrict__ anc,
                                               const float* __restrict__ depth,
                                               float* __restrict__ scratch){
  __shared__ uint2    s_rxx[NSTEP];        // (fx, sx) row-bound packs
  __shared__ uint2    s_cyy[NSTEP];        // (fy, sy) col-bound packs
  __shared__ float    s_lv[NSTEP];
  __shared__ uint4    s_clist[8][NSB];     // per-wave compacted entries {fy, sy, lv, t|flags}
  __shared__ int      s_nact[8];
  __shared__ float    s_acc[NE];           // per-block accumulator (LDS atomics, 8 writers max)

  int tid = threadIdx.x;
  for (int t = tid; t < NSTEP; t += 512) {
    unsigned vld, fx, fy, sx, sy; float lv;
    step_params(t, pred, anc, &vld, &lv, &fx, &fy, &sx, &sy);
    if (!vld) { fx = 0xFFFFu; sx = 0xFFFFu; }   // lo=0xFFFF,hi=0 -> empty row range
    s_rxx[t] = make_uint2(fx, sx);
    s_cyy[t] = make_uint2(fy, sy);
    s_lv[t] = lv;
  }
  for (int e = tid; e < NE; e += 512) s_acc[e] = 0.0f;
  __syncthreads();

  int half = tid >> 8;                         // 0 or 1: which row-unit
  int ru = blockIdx.x * 2 + half;              // row unit (b*256 + r); both halves share b
  int b = ru >> 8, r = ru & 255;
  int c = tid & 255, ln = tid & 63, w = tid >> 6;
  int wlo = c & ~63, whi = wlo + 64;           // this wave's col window

  // per-wave ordered compaction: keep steps that touch row r AND this wave's col window;
  // entry is self-contained so the inner loop never chases t back into s_cyy/s_lv.
  {
    int cnt = 0;
    #pragma unroll
    for (int g = 0; g < 3; ++g) {
      int m = g * 64 + ln;                 // m in [0,192)
      int t = b + 2 * m;                   // steps of batch b, increasing order
      uint2 rx = s_rxx[t];
      uint2 cy = s_cyy[t];
      bool rowF = (r >= (int)(rx.x & 0xffffu)) && (r < (int)(rx.x >> 16));
      bool rowS = (r >= (int)(rx.y & 0xffffu)) && (r < (int)(rx.y >> 16));
      bool fF = rowF && ((int)(cy.x & 0xffffu) < whi) && ((int)(cy.x >> 16) > wlo);
      bool fS = rowS && ((int)(cy.y & 0xffffu) < whi) && ((int)(cy.y >> 16) > wlo);
      bool f = fF || fS;
      unsigned long long msk = __ballot(f);
      int pos = (int)__popcll(msk & ((1ull << ln) - 1ull));
      if (f) {
        unsigned tf = (unsigned)t | (fF ? 512u : 0u) | (fS ? 1024u : 0u);
        s_clist[w][cnt + pos] = make_uint4(cy.x, cy.y, __float_as_uint(s_lv[t]), tf);
      }
      cnt += (int)__popcll(msk);
    }
    if (ln == 0) s_nact[w] = cnt;
  }

  float dt = depth[(size_t)ru * IMGN + c];
  bool okp = dt >= 1.0f;
  float ldt = okp ? logf(dt) : 0.0f;
  int ce = okp ? c : 0x7fffffff;      // folds depth-mask into the column test
  __syncthreads();
  int nact = s_nact[w];

  // paint-state: lvF/lvS start at ldt -> first paint and repaint share one formula:
  //   d1 = lv - lvF;  d2 = (lv-ldt)^2 - (lvF-ldt)^2 = d1*(lv + lvF - 2*ldt)
  bool hF = false, hS = false;        // only needed for first-paint counts
  float lvF = ldt, lvS = ldt;
  float ldt2 = 2.0f * ldt;
  uint4 cur = (nact > 0) ? s_clist[w][0] : make_uint4(0u, 0u, 0u, 0u);
  for (int idx = 0; idx < nact; ++idx) {
    uint4 nxt = (idx + 1 < nact) ? s_clist[w][idx + 1] : cur;  // prefetch in flight under DPP
    unsigned tf = cur.w;
    float lv = __uint_as_float(cur.z);
    bool inF = (tf & 512u)  && (ce >= (int)(cur.x & 0xffffu)) && (ce < (int)(cur.x >> 16));
    bool inS = (tf & 1024u) && (ce >= (int)(cur.y & 0xffffu)) && (ce < (int)(cur.y >> 16));
    if (__ballot(inF || inS) != 0ull) {
      unsigned long long mF = __ballot(inF && !hF);   // first paints (pre-update)
      unsigned long long mS = __ballot(inS && !hS);
      hF |= inF; hS |= inS;
      float d1 = inF ? (lv - lvF) : 0.0f;
      float d2 = d1 * (lv + lvF - ldt2);
      lvF = inF ? lv : lvF;
      float g1 = inS ? (lv - lvS) : 0.0f;
      float g2 = g1 * (lv + lvS - ldt2);
      lvS = inS ? lv : lvS;
      d1 = wsum_dpp(d1); d2 = wsum_dpp(d2);
      g1 = wsum_dpp(g1); g2 = wsum_dpp(g2);
      if (ln == 63) {
        float* base = s_acc + (int)(tf & 511u) * 6;
        float c0 = (float)__popcll(mF), c3 = (float)__popcll(mS);
        if (c0 != 0.f) atomicAdd(base + 0, c0);
        if (d1 != 0.f) atomicAdd(base + 1, d1);
        if (d2 != 0.f) atomicAdd(base + 2, d2);
        if (c3 != 0.f) atomicAdd(base + 3, c3);
        if (g1 != 0.f) atomicAdd(base + 4, g1);
        if (g2 != 0.f) atomicAdd(base + 5, g2);
      }
    }
    cur = nxt;
  }
  __syncthreads();
  // contiguous coalesced write: 9216 B per block
  for (int e = tid; e < NE; e += 512)
    scratch[(size_t)blockIdx.x * NE + e] = s_acc[e];
}

// ---------------- Kernel R: parallel reduce over kB blocks (COALESCED) ----------------
// grid = NRB=36 blocks x 256 threads. Block g owns e in [g*64, g*64+64);
// lane ln -> e = g*64+ln (lane-contiguous); wave w sums bk in [w*64, w*64+64).
__global__ __launch_bounds__(256) void yolo_kR(const float* __restrict__ scratch,
                                               double* __restrict__ reduced){
  __shared__ double part[4][64];
  int ln = threadIdx.x & 63, w = threadIdx.x >> 6;
  int e = blockIdx.x * 64 + ln;
  double s = 0.0;
  for (int bk = w * (NBB / 4); bk < (w + 1) * (NBB / 4); ++bk)
    s += (double)scratch[(size_t)bk * NE + e];
  part[w][ln] = s;
  __syncthreads();
  if (w == 0)
    reduced[e] = part[0][ln] + part[1][ln] + part[2][ln] + part[3][ln];
}

// ---------------- Kernel C: YOLO losses + prefix over steps + final loss ----------------
__global__ __launch_bounds__(384) void yolo_kC(const float* __restrict__ pred,
                                               const float* __restrict__ tgt,
                                               const float* __restrict__ anc,
                                               const double* __restrict__ reduced,
                                               float* __restrict__ out){
  __shared__ double sd[NE];
  __shared__ double chunk[6 * 6];     // [chunkIdx][comp], chunks of 64 steps
  __shared__ double rl[6], rc[6];
  __shared__ float  ry[6 * 6];
  int tid = threadIdx.x;
  for (int e = tid; e < NE; e += 384) sd[e] = reduced[e];

  // ---- YOLO losses; cell order (b,a,i,j) ----
  float s_obj, s_bce, s_bcecnt, s_objls, s_boxls, s_clsls;
  {
    int t = tid;
    int j = t % SN;
    int i = (t / SN) % SN;
    int a = (t / (SN * SN)) % AN;
    int b = t / (SN * SN * AN);
    const float* pc = pred + (size_t)((((b * AN + a) * SN + i) * SN + j)) * PRED_C;
    const float* tc = tgt  + (size_t)((((b * AN + a) * SN + i) * SN + j)) * 6;
    float t0 = tc[0];
    float objf  = (t0 == 1.0f) ? 1.0f : 0.0f;
    float noobj = (t0 == 0.0f) ? 1.0f : 0.0f;
    float p0 = pc[0];
    float l = fmaxf(p0, 0.0f) - p0 * t0 + log1pf(expf(-fabsf(p0)));
    s_bce = l * noobj; s_bcecnt = noobj; s_obj = objf;
    float aw = anc[2 * a], ah = anc[2 * a + 1];
    float sxp = 1.0f / (1.0f + expf(-pc[1]));
    float syp = 1.0f / (1.0f + expf(-pc[2]));
    float bw = expf(pc[3]) * aw, bh = expf(pc[4]) * ah;
    float ax1 = sxp - bw * 0.5f, ax2 = sxp + bw * 0.5f;
    float ay1 = syp - bh * 0.5f, ay2 = syp + bh * 0.5f;
    float bx1 = tc[1] - tc[3] * 0.5f, bx2 = tc[1] + tc[3] * 0.5f;
    float by1 = tc[2] - tc[4] * 0.5f, by2 = tc[2] + tc[4] * 0.5f;
    float iw = fmaxf(fminf(ax2, bx2) - fmaxf(ax1, bx1), 0.0f);
    float ih = fmaxf(fminf(ay2, by2) - fmaxf(ay1, by1), 0.0f);
    float inter = iw * ih;
    float areaA = fabsf((ax2 - ax1) * (ay2 - ay1));
    float areaB = fabsf((bx2 - bx1) * (by2 - by1));
    float iou = inter / (areaA + areaB - inter + 1e-6f);
    float sp0 = 1.0f / (1.0f + expf(-p0));
    float od = sp0 - iou * t0;
    s_objls = od * od * objf;
    float dx = sxp - tc[1], dy = syp - tc[2];
    float dw = pc[3] - logf(1e-16f + tc[3] / aw);
    float dh = pc[4] - logf(1e-16f + tc[4] / ah);
    s_boxls = (dx * dx + dy * dy + dw * dw + dh * dh) * objf;
    int lbl = (int)tc[5];
    float mx = -INFINITY;
    for (int c = 0; c < CN; ++c) mx = fmaxf(mx, pc[6 + c]);
    float se = 0.0f;
    for (int c = 0; c < CN; ++c) se += expf(pc[6 + c] - mx);
    float nll = mx + logf(se) - pc[6 + lbl];
    s_clsls = nll * objf;
  }
  {
    int wv = tid >> 6, ln = tid & 63;
    float vals[6] = { s_obj, s_bce, s_bcecnt, s_objls, s_boxls, s_clsls };
    #pragma unroll
    for (int ci = 0; ci < 6; ++ci) {
      float v = wredf(vals[ci]);
      if (ln == 0) ry[ci * 6 + wv] = v;
    }
  }

  // ---- valid bit for step tid (recomputed; only w/h chain matters) ----
  unsigned vld, ufx, ufy, usx, usy; float ulv;
  step_params(tid, pred, anc, &vld, &ulv, &ufx, &ufy, &usx, &usy);

  __syncthreads();
  // chunk sums: wave ch reduces chunk ch (64 steps) for all 6 comps in parallel
  {
    int ch = tid >> 6, ln = tid & 63;
    #pragma unroll
    for (int comp = 0; comp < 6; ++comp) {
      double v = wredd(sd[(ch * 64 + ln) * 6 + comp]);
      if (ln == 0) chunk[ch * 6 + comp] = v;
    }
  }
  __syncthreads();

  int t = tid;
  int ch = t >> 6;
  double P[6];
  #pragma unroll
  for (int comp = 0; comp < 6; ++comp) {
    double s = 0.0;
    for (int cc = 0; cc < ch; ++cc) s += chunk[cc * 6 + comp];
    for (int tt = (ch << 6); tt <= t; ++tt) s += sd[tt * 6 + comp];
    P[comp] = s;   // inclusive prefix: sums AFTER step t's paint
  }
  double lossd = 0.0, cntd = 0.0;
  {
    double n = P[0], Sg = P[1], Sg2 = P[2];
    double mean = Sg / fmax(n, 1.0);
    double var = (Sg2 - 2.0 * mean * Sg + n * mean * mean) / fmax(n - 1.0, 1.0);
    double Dg = var + 0.15 * mean * mean;
    double pl = 10.0 * sqrt(fmax(Dg, 1e-30));
    if (vld && n >= 2.0) { lossd += pl; cntd += 1.0; }
  }
  {
    double n = P[3], Sg = P[4], Sg2 = P[5];
    double mean = Sg / fmax(n, 1.0);
    double var = (Sg2 - 2.0 * mean * Sg + n * mean * mean) / fmax(n - 1.0, 1.0);
    double Dg = var + 0.15 * mean * mean;
    double pl = 10.0 * sqrt(fmax(Dg, 1e-30));
    if (vld && n >= 2.0) { lossd += pl; cntd += 1.0; }
  }
  int wv = tid >> 6, ln = tid & 63;
  double L = wredd(lossd), C = wredd(cntd);
  if (ln == 0) { rl[wv] = L; rc[wv] = C; }
  __syncthreads();
  if (tid == 0) {
    double totL = 0.0, totC = 0.0;
    for (int i = 0; i < 6; ++i) { totL += rl[i]; totC += rc[i]; }
    float yolo[6];
    #pragma unroll
    for (int ci = 0; ci < 6; ++ci) {
      float s = 0.0f;
      for (int w2 = 0; w2 < 6; ++w2) s += ry[ci * 6 + w2];
      yolo[ci] = s;
    }
    float dl = (float)(totL / fmax(totC, 1.0));
    float nobj = fmaxf(yolo[0], 1.0f);
    float noo  = yolo[1] / fmaxf(yolo[2], 1.0f);
    float objl = yolo[3] / nobj;
    float boxl = yolo[4] / (nobj * 4.0f);
    float clsl = yolo[5] / nobj;
    out[0] = 10.0f * boxl + objl + 10.0f * noo + clsl + dl;
  }
}

extern "C" void kernel_launch(void* const* d_in, const int* in_sizes, int n_in,
                              void* d_out, int out_size, void* d_ws, size_t ws_size,
                              hipStream_t stream) {
  const float* pred  = (const float*)d_in[0];
  const float* tgt   = (const float*)d_in[1];
  const float* anc   = (const float*)d_in[2];
  const float* depth = (const float*)d_in[3];

  float*  scratch = (float*)d_ws;                                          // NBB*NE floats = 2.36 MB
  double* reduced = (double*)((char*)d_ws + (size_t)NBB * NE * sizeof(float));  // NE doubles

  hipLaunchKernelGGL(yolo_kB, dim3(NBB), dim3(512), 0, stream, pred, anc, depth, scratch);
  hipLaunchKernelGGL(yolo_kR, dim3(NRB), dim3(256), 0, stream, scratch, reduced);
  hipLaunchKernelGGL(yolo_kC, dim3(1), dim3(384), 0, stream, pred, tgt, anc, reduced, (float*)d_out);
}

// Round 9
// 119.821 us; speedup vs baseline: 1.1119x; 1.1119x over previous
//
#include <hip/hip_runtime.h>
#include <cmath>

#define BN 2
#define AN 3
#define SN 8
#define CN 20
#define IMGN 256
#define NSTEP 384   // A*S*S*B steps in scan order (k,i,j,b)
#define PRED_C 26   // 6 + C
#define NE (NSTEP * 6)
#define NBB 256          // kB blocks (2 row-units each)
#define NSB (NSTEP / BN) // 192 steps per batch
#define NRB 36           // kR blocks (NE/64)

__device__ __forceinline__ float wredf(float v){
  #pragma unroll
  for (int o = 32; o; o >>= 1) v += __shfl_xor(v, o);
  return v;
}
__device__ __forceinline__ double wredd(double v){
  #pragma unroll
  for (int o = 32; o; o >>= 1) v += __shfl_xor(v, o);
  return v;
}
// rocPRIM-style gfx9 DPP wave sum: result valid in lane 63. Pure VALU, no LDS pipe.
// (correctness HW-verified: rounds 4-8 absmax 0.0)
__device__ __forceinline__ float wsum_dpp(float x){
  x += __int_as_float(__builtin_amdgcn_update_dpp(0, __float_as_int(x), 0x111, 0xf, 0xf, false)); // row_shr:1
  x += __int_as_float(__builtin_amdgcn_update_dpp(0, __float_as_int(x), 0x112, 0xf, 0xf, false)); // row_shr:2
  x += __int_as_float(__builtin_amdgcn_update_dpp(0, __float_as_int(x), 0x114, 0xf, 0xf, false)); // row_shr:4
  x += __int_as_float(__builtin_amdgcn_update_dpp(0, __float_as_int(x), 0x118, 0xf, 0xf, false)); // row_shr:8
  x += __int_as_float(__builtin_amdgcn_update_dpp(0, __float_as_int(x), 0x142, 0xa, 0xf, false)); // row_bcast:15
  x += __int_as_float(__builtin_amdgcn_update_dpp(0, __float_as_int(x), 0x143, 0xc, 0xf, false)); // row_bcast:31
  return x;
}
__device__ __forceinline__ int finitef(float x){
  return (__float_as_uint(x) & 0x7f800000u) != 0x7f800000u;
}
// exact replica of reference _axis_mask index computation (f32 trunc + negative wrap)
__device__ __forceinline__ unsigned axism(float lo, float hi){
  float lof = truncf(fminf(fmaxf(lo, -1e9f), 1e9f));
  float hif = truncf(fminf(fmaxf(hi, -1e9f), 1e9f));
  int l = (int)lof, h = (int)hif;
  l = (l < 0) ? max(IMGN + l, 0) : min(l, IMGN);
  h = (h < 0) ? max(IMGN + h, 0) : min(h, IMGN);
  return (unsigned)l | ((unsigned)h << 16);
}

// per-step scan parameters; scan order t = ((k*S + i)*S + j)*B + b
__device__ __forceinline__ void step_params(int t, const float* __restrict__ pred,
                                            const float* __restrict__ anc,
                                            unsigned* valid, float* lv,
                                            unsigned* fx, unsigned* fy,
                                            unsigned* sx, unsigned* sy){
  int b = t % BN;
  int j = (t / BN) % SN;
  int i = (t / (BN * SN)) % SN;
  int k = t / (BN * SN * SN);
  const float* pc = pred + (size_t)((((b * AN + k) * SN + i) * SN + j)) * PRED_C;
  float x = pc[1], y = pc[2], wv = pc[3], hv = pc[4], v = pc[5];
  float aw = anc[2 * k], ah = anc[2 * k + 1];
  // xy gets sigmoid applied (k+2) times total (1 before loop + k+1 in loop)
  for (int m = 0; m < k + 2; ++m) {
    x = 1.0f / (1.0f + expf(-x));
    y = 1.0f / (1.0f + expf(-y));
  }
  // wh: (k+1) iterations of exp(.)*anchor[k], in f32 (overflow -> inf -> invalid)
  for (int m = 0; m < k + 1; ++m) {
    wv = expf(wv) * aw;
    hv = expf(hv) * ah;
  }
  float cx = (x + (float)j) / 8.0f * 256.0f;
  float cy = (y + (float)i) / 8.0f * 256.0f;
  float w  = wv / 8.0f * 256.0f;
  float h  = hv / 8.0f * 256.0f;
  *valid = (w > 0.0f) && (h > 0.0f) && finitef(w) && finitef(h);
  *lv = logf(fmaxf(1.0f, v));
  // NOTE reference quirk: x-mask (from cx,w) indexes dp's ROW axis, y-mask the COL axis
  *fx = axism(cx - w / 2.0f, cx + w / 2.0f);
  *fy = axism(cy - h / 2.0f, cy + h / 2.0f);
  *sx = axism(cx - w / 4.0f, cx + w / 4.0f);
  *sy = axism(cy - h / 4.0f, cy + h / 4.0f);
}

// ---------------- Kernel B: per-pixel step scan -> per-block per-step delta partials ----------------
// 256 blocks x 512 threads; 2 row-units per block. Per-WAVE compacted self-contained 16B
// entries {fy, sy, lv, t|flags}. Inner loop processes entries PAIRWISE (8 independent DPP
// chains interleave) with ballot-gated F/S chain skipping and scalar first-paint masks.
// Sink = per-block LDS accumulator; one coalesced 9216 B scratch write per block.
__global__ __launch_bounds__(512) void yolo_kB(const float* __restrict__ pred,
                                               const float* __restrict__ anc,
                                               const float* __restrict__ depth,
                                               float* __restrict__ scratch){
  __shared__ uint2    s_rxx[NSTEP];        // (fx, sx) row-bound packs
  __shared__ uint2    s_cyy[NSTEP];        // (fy, sy) col-bound packs
  __shared__ float    s_lv[NSTEP];
  __shared__ uint4    s_clist[8][NSB];     // per-wave compacted entries {fy, sy, lv, t|flags}
  __shared__ int      s_nact[8];
  __shared__ float    s_acc[NE];           // per-block accumulator (LDS atomics, 8 writers max)

  int tid = threadIdx.x;
  for (int t = tid; t < NSTEP; t += 512) {
    unsigned vld, fx, fy, sx, sy; float lv;
    step_params(t, pred, anc, &vld, &lv, &fx, &fy, &sx, &sy);
    if (!vld) { fx = 0xFFFFu; sx = 0xFFFFu; }   // lo=0xFFFF,hi=0 -> empty row range
    s_rxx[t] = make_uint2(fx, sx);
    s_cyy[t] = make_uint2(fy, sy);
    s_lv[t] = lv;
  }
  for (int e = tid; e < NE; e += 512) s_acc[e] = 0.0f;
  __syncthreads();

  int half = tid >> 8;                         // 0 or 1: which row-unit
  int ru = blockIdx.x * 2 + half;              // row unit (b*256 + r); both halves share b
  int b = ru >> 8, r = ru & 255;
  int c = tid & 255, ln = tid & 63, w = tid >> 6;
  int wlo = c & ~63, whi = wlo + 64;           // this wave's col window

  // per-wave ordered compaction: keep steps that touch row r AND this wave's col window;
  // entry is self-contained so the inner loop never chases t back into s_cyy/s_lv.
  {
    int cnt = 0;
    #pragma unroll
    for (int g = 0; g < 3; ++g) {
      int m = g * 64 + ln;                 // m in [0,192)
      int t = b + 2 * m;                   // steps of batch b, increasing order
      uint2 rx = s_rxx[t];
      uint2 cy = s_cyy[t];
      bool rowF = (r >= (int)(rx.x & 0xffffu)) && (r < (int)(rx.x >> 16));
      bool rowS = (r >= (int)(rx.y & 0xffffu)) && (r < (int)(rx.y >> 16));
      bool fF = rowF && ((int)(cy.x & 0xffffu) < whi) && ((int)(cy.x >> 16) > wlo);
      bool fS = rowS && ((int)(cy.y & 0xffffu) < whi) && ((int)(cy.y >> 16) > wlo);
      bool f = fF || fS;
      unsigned long long msk = __ballot(f);
      int pos = (int)__popcll(msk & ((1ull << ln) - 1ull));
      if (f) {
        unsigned tf = (unsigned)t | (fF ? 512u : 0u) | (fS ? 1024u : 0u);
        s_clist[w][cnt + pos] = make_uint4(cy.x, cy.y, __float_as_uint(s_lv[t]), tf);
      }
      cnt += (int)__popcll(msk);
    }
    if (ln == 0) s_nact[w] = cnt;
  }

  float dt = depth[(size_t)ru * IMGN + c];
  bool okp = dt >= 1.0f;
  float ldt = okp ? logf(dt) : 0.0f;
  int ce = okp ? c : 0x7fffffff;      // folds depth-mask into the column test
  __syncthreads();
  int nact = s_nact[w];

  // paint-state: lvF/lvS start at ldt -> first paint and repaint share one formula:
  //   d1 = lv - lvF;  d2 = (lv-ldt)^2 - (lvF-ldt)^2 = d1*(lv + lvF - 2*ldt)
  // first-paint counts via SCALAR masks: mF = ballot(inF) & ~hFmask (no per-lane hF).
  unsigned long long hFmask = 0ull, hSmask = 0ull;
  float lvF = ldt, lvS = ldt;
  float ldt2 = 2.0f * ldt;
  int idx = 0;
  while (idx < nact) {
    uint4 E0 = s_clist[w][idx];
    bool two = (idx + 1 < nact);
    uint4 E1 = two ? s_clist[w][idx + 1] : make_uint4(0u, 0u, 0u, 0u); // flags=0 -> inert
    idx += 2;
    float lv0 = __uint_as_float(E0.z), lv1 = __uint_as_float(E1.z);
    bool inF0 = (E0.w & 512u)  && (ce >= (int)(E0.x & 0xffffu)) && (ce < (int)(E0.x >> 16));
    bool inS0 = (E0.w & 1024u) && (ce >= (int)(E0.y & 0xffffu)) && (ce < (int)(E0.y >> 16));
    bool inF1 = (E1.w & 512u)  && (ce >= (int)(E1.x & 0xffffu)) && (ce < (int)(E1.x >> 16));
    bool inS1 = (E1.w & 1024u) && (ce >= (int)(E1.y & 0xffffu)) && (ce < (int)(E1.y >> 16));
    unsigned long long aF0 = __ballot(inF0), aS0 = __ballot(inS0);
    unsigned long long aF1 = __ballot(inF1), aS1 = __ballot(inS1);
    if ((aF0 | aS0 | aF1 | aS1) == 0ull) continue;
    unsigned long long mF0 = aF0 & ~hFmask; hFmask |= aF0;
    unsigned long long mF1 = aF1 & ~hFmask; hFmask |= aF1;
    unsigned long long mS0 = aS0 & ~hSmask; hSmask |= aS0;
    unsigned long long mS1 = aS1 & ~hSmask; hSmask |= aS1;
    // sequential per-lane state updates (pair order matters)
    float d10 = inF0 ? (lv0 - lvF) : 0.0f;
    float d20 = d10 * (lv0 + lvF - ldt2);
    lvF = inF0 ? lv0 : lvF;
    float d11 = inF1 ? (lv1 - lvF) : 0.0f;
    float d21 = d11 * (lv1 + lvF - ldt2);
    lvF = inF1 ? lv1 : lvF;
    float g10 = inS0 ? (lv0 - lvS) : 0.0f;
    float g20 = g10 * (lv0 + lvS - ldt2);
    lvS = inS0 ? lv0 : lvS;
    float g11 = inS1 ? (lv1 - lvS) : 0.0f;
    float g21 = g11 * (lv1 + lvS - ldt2);
    lvS = inS1 ? lv1 : lvS;
    // gated reductions: 4 independent chains per branch interleave
    if (aF0 | aF1) { d10 = wsum_dpp(d10); d20 = wsum_dpp(d20);
                     d11 = wsum_dpp(d11); d21 = wsum_dpp(d21); }
    if (aS0 | aS1) { g10 = wsum_dpp(g10); g20 = wsum_dpp(g20);
                     g11 = wsum_dpp(g11); g21 = wsum_dpp(g21); }
    if (ln == 63) {
      float* b0 = s_acc + (int)(E0.w & 511u) * 6;
      float c00 = (float)__popcll(mF0), c30 = (float)__popcll(mS0);
      if (c00 != 0.f) atomicAdd(b0 + 0, c00);
      if (d10 != 0.f) atomicAdd(b0 + 1, d10);
      if (d20 != 0.f) atomicAdd(b0 + 2, d20);
      if (c30 != 0.f) atomicAdd(b0 + 3, c30);
      if (g10 != 0.f) atomicAdd(b0 + 4, g10);
      if (g20 != 0.f) atomicAdd(b0 + 5, g20);
      if (two) {
        float* b1 = s_acc + (int)(E1.w & 511u) * 6;
        float c01 = (float)__popcll(mF1), c31 = (float)__popcll(mS1);
        if (c01 != 0.f) atomicAdd(b1 + 0, c01);
        if (d11 != 0.f) atomicAdd(b1 + 1, d11);
        if (d21 != 0.f) atomicAdd(b1 + 2, d21);
        if (c31 != 0.f) atomicAdd(b1 + 3, c31);
        if (g11 != 0.f) atomicAdd(b1 + 4, g11);
        if (g21 != 0.f) atomicAdd(b1 + 5, g21);
      }
    }
  }
  __syncthreads();
  // contiguous coalesced write: 9216 B per block
  for (int e = tid; e < NE; e += 512)
    scratch[(size_t)blockIdx.x * NE + e] = s_acc[e];
}

// ---------------- Kernel R: parallel reduce over kB blocks (coalesced + unroll-8) ----------------
// grid = NRB=36 blocks x 256 threads. Block g owns e in [g*64, g*64+64);
// lane ln -> e = g*64+ln; wave w sums bk in [w*64, w*64+64) with 8 independent streams.
__global__ __launch_bounds__(256) void yolo_kR(const float* __restrict__ scratch,
                                               double* __restrict__ reduced){
  __shared__ double part[4][64];
  int ln = threadIdx.x & 63, w = threadIdx.x >> 6;
  int e = blockIdx.x * 64 + ln;
  const float* p = scratch + e;
  double s0 = 0, s1 = 0, s2 = 0, s3 = 0, s4 = 0, s5 = 0, s6 = 0, s7 = 0;
  int bk0 = w * (NBB / 4);
  for (int bk = bk0; bk < bk0 + NBB / 4; bk += 8) {
    s0 += (double)p[(size_t)(bk + 0) * NE];
    s1 += (double)p[(size_t)(bk + 1) * NE];
    s2 += (double)p[(size_t)(bk + 2) * NE];
    s3 += (double)p[(size_t)(bk + 3) * NE];
    s4 += (double)p[(size_t)(bk + 4) * NE];
    s5 += (double)p[(size_t)(bk + 5) * NE];
    s6 += (double)p[(size_t)(bk + 6) * NE];
    s7 += (double)p[(size_t)(bk + 7) * NE];
  }
  part[w][ln] = ((s0 + s1) + (s2 + s3)) + ((s4 + s5) + (s6 + s7));
  __syncthreads();
  if (w == 0)
    reduced[e] = part[0][ln] + part[1][ln] + part[2][ln] + part[3][ln];
}

// ---------------- Kernel C: YOLO losses + prefix over steps + final loss ----------------
__global__ __launch_bounds__(384) void yolo_kC(const float* __restrict__ pred,
                                               const float* __restrict__ tgt,
                                               const float* __restrict__ anc,
                                               const double* __restrict__ reduced,
                                               float* __restrict__ out){
  __shared__ double sd[NE];
  __shared__ double chunk[6 * 6];     // [chunkIdx][comp], chunks of 64 steps
  __shared__ double rl[6], rc[6];
  __shared__ float  ry[6 * 6];
  int tid = threadIdx.x;
  for (int e = tid; e < NE; e += 384) sd[e] = reduced[e];

  // ---- YOLO losses; cell order (b,a,i,j) ----
  float s_obj, s_bce, s_bcecnt, s_objls, s_boxls, s_clsls;
  {
    int t = tid;
    int j = t % SN;
    int i = (t / SN) % SN;
    int a = (t / (SN * SN)) % AN;
    int b = t / (SN * SN * AN);
    const float* pc = pred + (size_t)((((b * AN + a) * SN + i) * SN + j)) * PRED_C;
    const float* tc = tgt  + (size_t)((((b * AN + a) * SN + i) * SN + j)) * 6;
    float t0 = tc[0];
    float objf  = (t0 == 1.0f) ? 1.0f : 0.0f;
    float noobj = (t0 == 0.0f) ? 1.0f : 0.0f;
    float p0 = pc[0];
    float l = fmaxf(p0, 0.0f) - p0 * t0 + log1pf(expf(-fabsf(p0)));
    s_bce = l * noobj; s_bcecnt = noobj; s_obj = objf;
    float aw = anc[2 * a], ah = anc[2 * a + 1];
    float sxp = 1.0f / (1.0f + expf(-pc[1]));
    float syp = 1.0f / (1.0f + expf(-pc[2]));
    float bw = expf(pc[3]) * aw, bh = expf(pc[4]) * ah;
    float ax1 = sxp - bw * 0.5f, ax2 = sxp + bw * 0.5f;
    float ay1 = syp - bh * 0.5f, ay2 = syp + bh * 0.5f;
    float bx1 = tc[1] - tc[3] * 0.5f, bx2 = tc[1] + tc[3] * 0.5f;
    float by1 = tc[2] - tc[4] * 0.5f, by2 = tc[2] + tc[4] * 0.5f;
    float iw = fmaxf(fminf(ax2, bx2) - fmaxf(ax1, bx1), 0.0f);
    float ih = fmaxf(fminf(ay2, by2) - fmaxf(ay1, by1), 0.0f);
    float inter = iw * ih;
    float areaA = fabsf((ax2 - ax1) * (ay2 - ay1));
    float areaB = fabsf((bx2 - bx1) * (by2 - by1));
    float iou = inter / (areaA + areaB - inter + 1e-6f);
    float sp0 = 1.0f / (1.0f + expf(-p0));
    float od = sp0 - iou * t0;
    s_objls = od * od * objf;
    float dx = sxp - tc[1], dy = syp - tc[2];
    float dw = pc[3] - logf(1e-16f + tc[3] / aw);
    float dh = pc[4] - logf(1e-16f + tc[4] / ah);
    s_boxls = (dx * dx + dy * dy + dw * dw + dh * dh) * objf;
    int lbl = (int)tc[5];
    float mx = -INFINITY;
    for (int c = 0; c < CN; ++c) mx = fmaxf(mx, pc[6 + c]);
    float se = 0.0f;
    for (int c = 0; c < CN; ++c) se += expf(pc[6 + c] - mx);
    float nll = mx + logf(se) - pc[6 + lbl];
    s_clsls = nll * objf;
  }
  {
    int wv = tid >> 6, ln = tid & 63;
    float vals[6] = { s_obj, s_bce, s_bcecnt, s_objls, s_boxls, s_clsls };
    #pragma unroll
    for (int ci = 0; ci < 6; ++ci) {
      float v = wredf(vals[ci]);
      if (ln == 0) ry[ci * 6 + wv] = v;
    }
  }

  // ---- valid bit for step tid (recomputed; only w/h chain matters) ----
  unsigned vld, ufx, ufy, usx, usy; float ulv;
  step_params(tid, pred, anc, &vld, &ulv, &ufx, &ufy, &usx, &usy);

  __syncthreads();
  // chunk sums: wave ch reduces chunk ch (64 steps) for all 6 comps in parallel
  {
    int ch = tid >> 6, ln = tid & 63;
    #pragma unroll
    for (int comp = 0; comp < 6; ++comp) {
      double v = wredd(sd[(ch * 64 + ln) * 6 + comp]);
      if (ln == 0) chunk[ch * 6 + comp] = v;
    }
  }
  __syncthreads();

  int t = tid;
  int ch = t >> 6;
  double P[6];
  #pragma unroll
  for (int comp = 0; comp < 6; ++comp) {
    double s = 0.0;
    for (int cc = 0; cc < ch; ++cc) s += chunk[cc * 6 + comp];
    for (int tt = (ch << 6); tt <= t; ++tt) s += sd[tt * 6 + comp];
    P[comp] = s;   // inclusive prefix: sums AFTER step t's paint
  }
  double lossd = 0.0, cntd = 0.0;
  {
    double n = P[0], Sg = P[1], Sg2 = P[2];
    double mean = Sg / fmax(n, 1.0);
    double var = (Sg2 - 2.0 * mean * Sg + n * mean * mean) / fmax(n - 1.0, 1.0);
    double Dg = var + 0.15 * mean * mean;
    double pl = 10.0 * sqrt(fmax(Dg, 1e-30));
    if (vld && n >= 2.0) { lossd += pl; cntd += 1.0; }
  }
  {
    double n = P[3], Sg = P[4], Sg2 = P[5];
    double mean = Sg / fmax(n, 1.0);
    double var = (Sg2 - 2.0 * mean * Sg + n * mean * mean) / fmax(n - 1.0, 1.0);
    double Dg = var + 0.15 * mean * mean;
    double pl = 10.0 * sqrt(fmax(Dg, 1e-30));
    if (vld && n >= 2.0) { lossd += pl; cntd += 1.0; }
  }
  int wv = tid >> 6, ln = tid & 63;
  double L = wredd(lossd), C = wredd(cntd);
  if (ln == 0) { rl[wv] = L; rc[wv] = C; }
  __syncthreads();
  if (tid == 0) {
    double totL = 0.0, totC = 0.0;
    for (int i = 0; i < 6; ++i) { totL += rl[i]; totC += rc[i]; }
    float yolo[6];
    #pragma unroll
    for (int ci = 0; ci < 6; ++ci) {
      float s = 0.0f;
      for (int w2 = 0; w2 < 6; ++w2) s += ry[ci * 6 + w2];
      yolo[ci] = s;
    }
    float dl = (float)(totL / fmax(totC, 1.0));
    float nobj = fmaxf(yolo[0], 1.0f);
    float noo  = yolo[1] / fmaxf(yolo[2], 1.0f);
    float objl = yolo[3] / nobj;
    float boxl = yolo[4] / (nobj * 4.0f);
    float clsl = yolo[5] / nobj;
    out[0] = 10.0f * boxl + objl + 10.0f * noo + clsl + dl;
  }
}

extern "C" void kernel_launch(void* const* d_in, const int* in_sizes, int n_in,
                              void* d_out, int out_size, void* d_ws, size_t ws_size,
                              hipStream_t stream) {
  const float* pred  = (const float*)d_in[0];
  const float* tgt   = (const float*)d_in[1];
  const float* anc   = (const float*)d_in[2];
  const float* depth = (const float*)d_in[3];

  float*  scratch = (float*)d_ws;                                          // NBB*NE floats = 2.36 MB
  double* reduced = (double*)((char*)d_ws + (size_t)NBB * NE * sizeof(float));  // NE doubles

  hipLaunchKernelGGL(yolo_kB, dim3(NBB), dim3(512), 0, stream, pred, anc, depth, scratch);
  hipLaunchKernelGGL(yolo_kR, dim3(NRB), dim3(256), 0, stream, scratch, reduced);
  hipLaunchKernelGGL(yolo_kC, dim3(1), dim3(384), 0, stream, pred, tgt, anc, reduced, (float*)d_out);
}

// Round 10
// 112.201 us; speedup vs baseline: 1.1874x; 1.0679x over previous
//
#include <hip/hip_runtime.h>
#include <cmath>

#define BN 2
#define AN 3
#define SN 8
#define CN 20
#define IMGN 256
#define NSTEP 384   // A*S*S*B steps in scan order (k,i,j,b)
#define PRED_C 26   // 6 + C
#define NE (NSTEP * 6)
#define NB (BN * IMGN)   // 512 kB blocks, one row-unit each
#define NSB (NSTEP / BN) // 192 steps per batch
#define NRB 36           // kR blocks (NE/64)

__device__ __forceinline__ float wredf(float v){
  #pragma unroll
  for (int o = 32; o; o >>= 1) v += __shfl_xor(v, o);
  return v;
}
__device__ __forceinline__ double wredd(double v){
  #pragma unroll
  for (int o = 32; o; o >>= 1) v += __shfl_xor(v, o);
  return v;
}
// rocPRIM-style gfx9 DPP wave sum: result valid in lane 63. Pure VALU, no LDS pipe.
// (correctness HW-verified: rounds 4-9 absmax 0.0)
__device__ __forceinline__ float wsum_dpp(float x){
  x += __int_as_float(__builtin_amdgcn_update_dpp(0, __float_as_int(x), 0x111, 0xf, 0xf, false)); // row_shr:1
  x += __int_as_float(__builtin_amdgcn_update_dpp(0, __float_as_int(x), 0x112, 0xf, 0xf, false)); // row_shr:2
  x += __int_as_float(__builtin_amdgcn_update_dpp(0, __float_as_int(x), 0x114, 0xf, 0xf, false)); // row_shr:4
  x += __int_as_float(__builtin_amdgcn_update_dpp(0, __float_as_int(x), 0x118, 0xf, 0xf, false)); // row_shr:8
  x += __int_as_float(__builtin_amdgcn_update_dpp(0, __float_as_int(x), 0x142, 0xa, 0xf, false)); // row_bcast:15
  x += __int_as_float(__builtin_amdgcn_update_dpp(0, __float_as_int(x), 0x143, 0xc, 0xf, false)); // row_bcast:31
  return x;
}
__device__ __forceinline__ int finitef(float x){
  return (__float_as_uint(x) & 0x7f800000u) != 0x7f800000u;
}
// exact replica of reference _axis_mask index computation (f32 trunc + negative wrap)
__device__ __forceinline__ unsigned axism(float lo, float hi){
  float lof = truncf(fminf(fmaxf(lo, -1e9f), 1e9f));
  float hif = truncf(fminf(fmaxf(hi, -1e9f), 1e9f));
  int l = (int)lof, h = (int)hif;
  l = (l < 0) ? max(IMGN + l, 0) : min(l, IMGN);
  h = (h < 0) ? max(IMGN + h, 0) : min(h, IMGN);
  return (unsigned)l | ((unsigned)h << 16);
}

// per-step scan parameters; scan order t = ((k*S + i)*S + j)*B + b
__device__ __forceinline__ void step_params(int t, const float* __restrict__ pred,
                                            const float* __restrict__ anc,
                                            unsigned* valid, float* lv,
                                            unsigned* fx, unsigned* fy,
                                            unsigned* sx, unsigned* sy){
  int b = t % BN;
  int j = (t / BN) % SN;
  int i = (t / (BN * SN)) % SN;
  int k = t / (BN * SN * SN);
  const float* pc = pred + (size_t)((((b * AN + k) * SN + i) * SN + j)) * PRED_C;
  float x = pc[1], y = pc[2], wv = pc[3], hv = pc[4], v = pc[5];
  float aw = anc[2 * k], ah = anc[2 * k + 1];
  // xy gets sigmoid applied (k+2) times total (1 before loop + k+1 in loop)
  for (int m = 0; m < k + 2; ++m) {
    x = 1.0f / (1.0f + expf(-x));
    y = 1.0f / (1.0f + expf(-y));
  }
  // wh: (k+1) iterations of exp(.)*anchor[k], in f32 (overflow -> inf -> invalid)
  for (int m = 0; m < k + 1; ++m) {
    wv = expf(wv) * aw;
    hv = expf(hv) * ah;
  }
  float cx = (x + (float)j) / 8.0f * 256.0f;
  float cy = (y + (float)i) / 8.0f * 256.0f;
  float w  = wv / 8.0f * 256.0f;
  float h  = hv / 8.0f * 256.0f;
  *valid = (w > 0.0f) && (h > 0.0f) && finitef(w) && finitef(h);
  *lv = logf(fmaxf(1.0f, v));
  // NOTE reference quirk: x-mask (from cx,w) indexes dp's ROW axis, y-mask the COL axis
  *fx = axism(cx - w / 2.0f, cx + w / 2.0f);
  *fy = axism(cy - h / 2.0f, cy + h / 2.0f);
  *sx = axism(cx - w / 4.0f, cx + w / 4.0f);
  *sy = axism(cy - h / 4.0f, cy + h / 4.0f);
}

// ---------------- Kernel B: per-pixel step scan -> per-block per-step delta partials ----------------
// 512 blocks x 512 threads; ONE row-unit per block. TYPE-SPLIT waves: waves 0-3 process the
// FULL rect (comps 0-2) over the 4 col-windows, waves 4-7 the SMALL rect (comps 3-5).
// F and S are independent reductions (separate state, separate acc comps) -> 2x occupancy
// (4 waves/SIMD) and half the DPP chains per wave. Per-wave compacted self-contained entries
// {bounds, lv, t}; pairwise inner loop (4 independent DPP chains); scalar first-paint masks.
__global__ __launch_bounds__(512) void yolo_kB(const float* __restrict__ pred,
                                               const float* __restrict__ anc,
                                               const float* __restrict__ depth,
                                               float* __restrict__ scratch){
  __shared__ uint2    s_rxx[NSTEP];        // (fx, sx) row-bound packs
  __shared__ uint2    s_cyy[NSTEP];        // (fy, sy) col-bound packs
  __shared__ float    s_lv[NSTEP];
  __shared__ uint4    s_clist[8][NSB];     // per-wave compacted entries {bounds, lv, t, -}
  __shared__ int      s_nact[8];
  __shared__ float    s_acc[NE];           // per-block accumulator (LDS atomics)

  int tid = threadIdx.x;
  for (int t = tid; t < NSTEP; t += 512) {
    unsigned vld, fx, fy, sx, sy; float lv;
    step_params(t, pred, anc, &vld, &lv, &fx, &fy, &sx, &sy);
    if (!vld) { fx = 0xFFFFu; sx = 0xFFFFu; }   // lo=0xFFFF,hi=0 -> empty row range
    s_rxx[t] = make_uint2(fx, sx);
    s_cyy[t] = make_uint2(fy, sy);
    s_lv[t] = lv;
  }
  for (int e = tid; e < NE; e += 512) s_acc[e] = 0.0f;
  __syncthreads();

  int ru = blockIdx.x;          // one row-unit per block
  int b = ru >> 8, r = ru & 255;
  int ln = tid & 63, w = tid >> 6;
  int win = w & 3, type = w >> 2;              // type: 0=F, 1=S
  int wlo = win * 64, whi = wlo + 64;
  int c = wlo + ln;

  // per-wave ordered compaction: steps whose TYPE-rect touches row r AND this col window
  {
    int cnt = 0;
    #pragma unroll
    for (int g = 0; g < 3; ++g) {
      int m = g * 64 + ln;                 // m in [0,192)
      int t = b + 2 * m;                   // steps of batch b, increasing order
      uint2 rx = s_rxx[t];
      uint2 cy = s_cyy[t];
      unsigned rb = type ? rx.y : rx.x;    // row bounds for this type
      unsigned cb = type ? cy.y : cy.x;    // col bounds for this type
      bool rowT = (r >= (int)(rb & 0xffffu)) && (r < (int)(rb >> 16));
      bool f = rowT && ((int)(cb & 0xffffu) < whi) && ((int)(cb >> 16) > wlo);
      unsigned long long msk = __ballot(f);
      int pos = (int)__popcll(msk & ((1ull << ln) - 1ull));
      if (f) s_clist[w][cnt + pos] = make_uint4(cb, __float_as_uint(s_lv[t]), (unsigned)t, 0u);
      cnt += (int)__popcll(msk);
    }
    if (ln == 0) s_nact[w] = cnt;
  }

  float dt = depth[(size_t)ru * IMGN + c];
  bool okp = dt >= 1.0f;
  float ldt = okp ? logf(dt) : 0.0f;
  int ce = okp ? c : 0x7fffffff;      // folds depth-mask into the column test
  __syncthreads();
  int nact = s_nact[w];

  // paint-state: lvP starts at ldt -> first paint and repaint share one formula:
  //   d1 = lv - lvP;  d2 = (lv-ldt)^2 - (lvP-ldt)^2 = d1*(lv + lvP - 2*ldt)
  // first-paint counts via SCALAR mask: m = ballot(in) & ~hmask.
  unsigned long long hmask = 0ull;
  float lvP = ldt;
  float ldt2 = 2.0f * ldt;
  int coff = type * 3;                // acc comps 0-2 (F) or 3-5 (S)
  int idx = 0;
  while (idx < nact) {
    uint4 E0 = s_clist[w][idx];
    bool two = (idx + 1 < nact);
    uint4 E1 = two ? s_clist[w][idx + 1] : make_uint4(0xFFFFu, 0u, 0u, 0u); // empty bounds -> inert
    idx += 2;
    float lv0 = __uint_as_float(E0.y), lv1 = __uint_as_float(E1.y);
    bool in0 = (ce >= (int)(E0.x & 0xffffu)) && (ce < (int)(E0.x >> 16));
    bool in1 = (ce >= (int)(E1.x & 0xffffu)) && (ce < (int)(E1.x >> 16));
    unsigned long long a0 = __ballot(in0), a1 = __ballot(in1);
    if ((a0 | a1) == 0ull) continue;
    unsigned long long m0 = a0 & ~hmask; hmask |= a0;
    unsigned long long m1 = a1 & ~hmask; hmask |= a1;
    // sequential per-lane state updates (pair order matters)
    float d10 = in0 ? (lv0 - lvP) : 0.0f;
    float d20 = d10 * (lv0 + lvP - ldt2);
    lvP = in0 ? lv0 : lvP;
    float d11 = in1 ? (lv1 - lvP) : 0.0f;
    float d21 = d11 * (lv1 + lvP - ldt2);
    lvP = in1 ? lv1 : lvP;
    // 4 independent DPP chains interleave
    d10 = wsum_dpp(d10); d20 = wsum_dpp(d20);
    d11 = wsum_dpp(d11); d21 = wsum_dpp(d21);
    if (ln == 63) {
      float* b0 = s_acc + (int)E0.z * 6 + coff;
      float c0 = (float)__popcll(m0);
      if (c0  != 0.f) atomicAdd(b0 + 0, c0);
      if (d10 != 0.f) atomicAdd(b0 + 1, d10);
      if (d20 != 0.f) atomicAdd(b0 + 2, d20);
      if (two) {
        float* b1 = s_acc + (int)E1.z * 6 + coff;
        float c1 = (float)__popcll(m1);
        if (c1  != 0.f) atomicAdd(b1 + 0, c1);
        if (d11 != 0.f) atomicAdd(b1 + 1, d11);
        if (d21 != 0.f) atomicAdd(b1 + 2, d21);
      }
    }
  }
  __syncthreads();
  // contiguous coalesced write: 9216 B per block
  for (int e = tid; e < NE; e += 512)
    scratch[(size_t)blockIdx.x * NE + e] = s_acc[e];
}

// ---------------- Kernel R: parallel reduce over kB blocks (coalesced + unroll-8) ----------------
// grid = NRB=36 blocks x 256 threads. Block g owns e in [g*64, g*64+64);
// lane ln -> e = g*64+ln; wave w sums bk in [w*128, w*128+128) with 8 independent streams.
__global__ __launch_bounds__(256) void yolo_kR(const float* __restrict__ scratch,
                                               double* __restrict__ reduced){
  __shared__ double part[4][64];
  int ln = threadIdx.x & 63, w = threadIdx.x >> 6;
  int e = blockIdx.x * 64 + ln;
  const float* p = scratch + e;
  double s0 = 0, s1 = 0, s2 = 0, s3 = 0, s4 = 0, s5 = 0, s6 = 0, s7 = 0;
  int bk0 = w * (NB / 4);
  for (int bk = bk0; bk < bk0 + NB / 4; bk += 8) {
    s0 += (double)p[(size_t)(bk + 0) * NE];
    s1 += (double)p[(size_t)(bk + 1) * NE];
    s2 += (double)p[(size_t)(bk + 2) * NE];
    s3 += (double)p[(size_t)(bk + 3) * NE];
    s4 += (double)p[(size_t)(bk + 4) * NE];
    s5 += (double)p[(size_t)(bk + 5) * NE];
    s6 += (double)p[(size_t)(bk + 6) * NE];
    s7 += (double)p[(size_t)(bk + 7) * NE];
  }
  part[w][ln] = ((s0 + s1) + (s2 + s3)) + ((s4 + s5) + (s6 + s7));
  __syncthreads();
  if (w == 0)
    reduced[e] = part[0][ln] + part[1][ln] + part[2][ln] + part[3][ln];
}

// ---------------- Kernel C: YOLO losses + prefix over steps + final loss ----------------
__global__ __launch_bounds__(384) void yolo_kC(const float* __restrict__ pred,
                                               const float* __restrict__ tgt,
                                               const float* __restrict__ anc,
                                               const double* __restrict__ reduced,
                                               float* __restrict__ out){
  __shared__ double sd[NE];
  __shared__ double chunk[6 * 6];     // [chunkIdx][comp], chunks of 64 steps
  __shared__ double rl[6], rc[6];
  __shared__ float  ry[6 * 6];
  int tid = threadIdx.x;
  for (int e = tid; e < NE; e += 384) sd[e] = reduced[e];

  // ---- YOLO losses; cell order (b,a,i,j) ----
  float s_obj, s_bce, s_bcecnt, s_objls, s_boxls, s_clsls;
  {
    int t = tid;
    int j = t % SN;
    int i = (t / SN) % SN;
    int a = (t / (SN * SN)) % AN;
    int b = t / (SN * SN * AN);
    const float* pc = pred + (size_t)((((b * AN + a) * SN + i) * SN + j)) * PRED_C;
    const float* tc = tgt  + (size_t)((((b * AN + a) * SN + i) * SN + j)) * 6;
    float t0 = tc[0];
    float objf  = (t0 == 1.0f) ? 1.0f : 0.0f;
    float noobj = (t0 == 0.0f) ? 1.0f : 0.0f;
    float p0 = pc[0];
    float l = fmaxf(p0, 0.0f) - p0 * t0 + log1pf(expf(-fabsf(p0)));
    s_bce = l * noobj; s_bcecnt = noobj; s_obj = objf;
    float aw = anc[2 * a], ah = anc[2 * a + 1];
    float sxp = 1.0f / (1.0f + expf(-pc[1]));
    float syp = 1.0f / (1.0f + expf(-pc[2]));
    float bw = expf(pc[3]) * aw, bh = expf(pc[4]) * ah;
    float ax1 = sxp - bw * 0.5f, ax2 = sxp + bw * 0.5f;
    float ay1 = syp - bh * 0.5f, ay2 = syp + bh * 0.5f;
    float bx1 = tc[1] - tc[3] * 0.5f, bx2 = tc[1] + tc[3] * 0.5f;
    float by1 = tc[2] - tc[4] * 0.5f, by2 = tc[2] + tc[4] * 0.5f;
    float iw = fmaxf(fminf(ax2, bx2) - fmaxf(ax1, bx1), 0.0f);
    float ih = fmaxf(fminf(ay2, by2) - fmaxf(ay1, by1), 0.0f);
    float inter = iw * ih;
    float areaA = fabsf((ax2 - ax1) * (ay2 - ay1));
    float areaB = fabsf((bx2 - bx1) * (by2 - by1));
    float iou = inter / (areaA + areaB - inter + 1e-6f);
    float sp0 = 1.0f / (1.0f + expf(-p0));
    float od = sp0 - iou * t0;
    s_objls = od * od * objf;
    float dx = sxp - tc[1], dy = syp - tc[2];
    float dw = pc[3] - logf(1e-16f + tc[3] / aw);
    float dh = pc[4] - logf(1e-16f + tc[4] / ah);
    s_boxls = (dx * dx + dy * dy + dw * dw + dh * dh) * objf;
    int lbl = (int)tc[5];
    float mx = -INFINITY;
    for (int c = 0; c < CN; ++c) mx = fmaxf(mx, pc[6 + c]);
    float se = 0.0f;
    for (int c = 0; c < CN; ++c) se += expf(pc[6 + c] - mx);
    float nll = mx + logf(se) - pc[6 + lbl];
    s_clsls = nll * objf;
  }
  {
    int wv = tid >> 6, ln = tid & 63;
    float vals[6] = { s_obj, s_bce, s_bcecnt, s_objls, s_boxls, s_clsls };
    #pragma unroll
    for (int ci = 0; ci < 6; ++ci) {
      float v = wredf(vals[ci]);
      if (ln == 0) ry[ci * 6 + wv] = v;
    }
  }

  // ---- valid bit for step tid (recomputed; only w/h chain matters) ----
  unsigned vld, ufx, ufy, usx, usy; float ulv;
  step_params(tid, pred, anc, &vld, &ulv, &ufx, &ufy, &usx, &usy);

  __syncthreads();
  // chunk sums: wave ch reduces chunk ch (64 steps) for all 6 comps in parallel
  {
    int ch = tid >> 6, ln = tid & 63;
    #pragma unroll
    for (int comp = 0; comp < 6; ++comp) {
      double v = wredd(sd[(ch * 64 + ln) * 6 + comp]);
      if (ln == 0) chunk[ch * 6 + comp] = v;
    }
  }
  __syncthreads();

  int t = tid;
  int ch = t >> 6;
  double P[6];
  #pragma unroll
  for (int comp = 0; comp < 6; ++comp) {
    double s = 0.0;
    for (int cc = 0; cc < ch; ++cc) s += chunk[cc * 6 + comp];
    for (int tt = (ch << 6); tt <= t; ++tt) s += sd[tt * 6 + comp];
    P[comp] = s;   // inclusive prefix: sums AFTER step t's paint
  }
  double lossd = 0.0, cntd = 0.0;
  {
    double n = P[0], Sg = P[1], Sg2 = P[2];
    double mean = Sg / fmax(n, 1.0);
    double var = (Sg2 - 2.0 * mean * Sg + n * mean * mean) / fmax(n - 1.0, 1.0);
    double Dg = var + 0.15 * mean * mean;
    double pl = 10.0 * sqrt(fmax(Dg, 1e-30));
    if (vld && n >= 2.0) { lossd += pl; cntd += 1.0; }
  }
  {
    double n = P[3], Sg = P[4], Sg2 = P[5];
    double mean = Sg / fmax(n, 1.0);
    double var = (Sg2 - 2.0 * mean * Sg + n * mean * mean) / fmax(n - 1.0, 1.0);
    double Dg = var + 0.15 * mean * mean;
    double pl = 10.0 * sqrt(fmax(Dg, 1e-30));
    if (vld && n >= 2.0) { lossd += pl; cntd += 1.0; }
  }
  int wv = tid >> 6, ln = tid & 63;
  double L = wredd(lossd), C = wredd(cntd);
  if (ln == 0) { rl[wv] = L; rc[wv] = C; }
  __syncthreads();
  if (tid == 0) {
    double totL = 0.0, totC = 0.0;
    for (int i = 0; i < 6; ++i) { totL += rl[i]; totC += rc[i]; }
    float yolo[6];
    #pragma unroll
    for (int ci = 0; ci < 6; ++ci) {
      float s = 0.0f;
      for (int w2 = 0; w2 < 6; ++w2) s += ry[ci * 6 + w2];
      yolo[ci] = s;
    }
    float dl = (float)(totL / fmax(totC, 1.0));
    float nobj = fmaxf(yolo[0], 1.0f);
    float noo  = yolo[1] / fmaxf(yolo[2], 1.0f);
    float objl = yolo[3] / nobj;
    float boxl = yolo[4] / (nobj * 4.0f);
    float clsl = yolo[5] / nobj;
    out[0] = 10.0f * boxl + objl + 10.0f * noo + clsl + dl;
  }
}

extern "C" void kernel_launch(void* const* d_in, const int* in_sizes, int n_in,
                              void* d_out, int out_size, void* d_ws, size_t ws_size,
                              hipStream_t stream) {
  const float* pred  = (const float*)d_in[0];
  const float* tgt   = (const float*)d_in[1];
  const float* anc   = (const float*)d_in[2];
  const float* depth = (const float*)d_in[3];

  float*  scratch = (float*)d_ws;                                          // NB*NE floats = 4.72 MB
  double* reduced = (double*)((char*)d_ws + (size_t)NB * NE * sizeof(float));   // NE doubles

  hipLaunchKernelGGL(yolo_kB, dim3(NB), dim3(512), 0, stream, pred, anc, depth, scratch);
  hipLaunchKernelGGL(yolo_kR, dim3(NRB), dim3(256), 0, stream, scratch, reduced);
  hipLaunchKernelGGL(yolo_kC, dim3(1), dim3(384), 0, stream, pred, tgt, anc, reduced, (float*)d_out);
}

// Round 11
// 112.187 us; speedup vs baseline: 1.1876x; 1.0001x over previous
//
#include <hip/hip_runtime.h>
#include <cmath>

#define BN 2
#define AN 3
#define SN 8
#define CN 20
#define IMGN 256
#define NSTEP 384   // A*S*S*B steps in scan order (k,i,j,b)
#define PRED_C 26   // 6 + C
#define NE (NSTEP * 6)
#define NB (BN * IMGN)   // 512 kB blocks, one row-unit each
#define NSB (NSTEP / BN) // 192 steps per batch
#define NRB 36           // kR blocks (NE/64)

__device__ __forceinline__ float wredf(float v){
  #pragma unroll
  for (int o = 32; o; o >>= 1) v += __shfl_xor(v, o);
  return v;
}
__device__ __forceinline__ double wredd(double v){
  #pragma unroll
  for (int o = 32; o; o >>= 1) v += __shfl_xor(v, o);
  return v;
}
// rocPRIM-style gfx9 DPP wave sum: result valid in lane 63. Pure VALU, no LDS pipe.
// (correctness HW-verified: rounds 4-10 absmax 0.0)
__device__ __forceinline__ float wsum_dpp(float x){
  x += __int_as_float(__builtin_amdgcn_update_dpp(0, __float_as_int(x), 0x111, 0xf, 0xf, false)); // row_shr:1
  x += __int_as_float(__builtin_amdgcn_update_dpp(0, __float_as_int(x), 0x112, 0xf, 0xf, false)); // row_shr:2
  x += __int_as_float(__builtin_amdgcn_update_dpp(0, __float_as_int(x), 0x114, 0xf, 0xf, false)); // row_shr:4
  x += __int_as_float(__builtin_amdgcn_update_dpp(0, __float_as_int(x), 0x118, 0xf, 0xf, false)); // row_shr:8
  x += __int_as_float(__builtin_amdgcn_update_dpp(0, __float_as_int(x), 0x142, 0xa, 0xf, false)); // row_bcast:15
  x += __int_as_float(__builtin_amdgcn_update_dpp(0, __float_as_int(x), 0x143, 0xc, 0xf, false)); // row_bcast:31
  return x;
}
__device__ __forceinline__ int finitef(float x){
  return (__float_as_uint(x) & 0x7f800000u) != 0x7f800000u;
}
// exact replica of reference _axis_mask index computation (f32 trunc + negative wrap)
__device__ __forceinline__ unsigned axism(float lo, float hi){
  float lof = truncf(fminf(fmaxf(lo, -1e9f), 1e9f));
  float hif = truncf(fminf(fmaxf(hi, -1e9f), 1e9f));
  int l = (int)lof, h = (int)hif;
  l = (l < 0) ? max(IMGN + l, 0) : min(l, IMGN);
  h = (h < 0) ? max(IMGN + h, 0) : min(h, IMGN);
  return (unsigned)l | ((unsigned)h << 16);
}

// per-step scan parameters; scan order t = ((k*S + i)*S + j)*B + b
__device__ __forceinline__ void step_params(int t, const float* __restrict__ pred,
                                            const float* __restrict__ anc,
                                            unsigned* valid, float* lv,
                                            unsigned* fx, unsigned* fy,
                                            unsigned* sx, unsigned* sy){
  int b = t % BN;
  int j = (t / BN) % SN;
  int i = (t / (BN * SN)) % SN;
  int k = t / (BN * SN * SN);
  const float* pc = pred + (size_t)((((b * AN + k) * SN + i) * SN + j)) * PRED_C;
  float x = pc[1], y = pc[2], wv = pc[3], hv = pc[4], v = pc[5];
  float aw = anc[2 * k], ah = anc[2 * k + 1];
  // xy gets sigmoid applied (k+2) times total (1 before loop + k+1 in loop)
  for (int m = 0; m < k + 2; ++m) {
    x = 1.0f / (1.0f + expf(-x));
    y = 1.0f / (1.0f + expf(-y));
  }
  // wh: (k+1) iterations of exp(.)*anchor[k], in f32 (overflow -> inf -> invalid)
  for (int m = 0; m < k + 1; ++m) {
    wv = expf(wv) * aw;
    hv = expf(hv) * ah;
  }
  float cx = (x + (float)j) / 8.0f * 256.0f;
  float cy = (y + (float)i) / 8.0f * 256.0f;
  float w  = wv / 8.0f * 256.0f;
  float h  = hv / 8.0f * 256.0f;
  *valid = (w > 0.0f) && (h > 0.0f) && finitef(w) && finitef(h);
  *lv = logf(fmaxf(1.0f, v));
  // NOTE reference quirk: x-mask (from cx,w) indexes dp's ROW axis, y-mask the COL axis
  *fx = axism(cx - w / 2.0f, cx + w / 2.0f);
  *fy = axism(cy - h / 2.0f, cy + h / 2.0f);
  *sx = axism(cx - w / 4.0f, cx + w / 4.0f);
  *sy = axism(cy - h / 4.0f, cy + h / 4.0f);
}

// ---------------- Kernel B: per-pixel step scan -> per-block per-step delta partials ----------------
// 512 blocks x 512 threads; ONE row-unit per block. TYPE-SPLIT waves (0-3: full rect / comps
// 0-2; 4-7: small rect / comps 3-5) over 4 col-windows. Staging covers ONLY batch-b's 192
// steps. Per-wave compacted lists padded to x4 with inert entries; QUAD inner loop keeps 8
// independent DPP chains in flight. Sink = per-block LDS acc; one coalesced 9216B write.
__global__ __launch_bounds__(512) void yolo_kB(const float* __restrict__ pred,
                                               const float* __restrict__ anc,
                                               const float* __restrict__ depth,
                                               float* __restrict__ scratch){
  __shared__ uint2    s_rxx[NSB];          // (fx, sx) row-bound packs, batch-b steps only
  __shared__ uint2    s_cyy[NSB];          // (fy, sy) col-bound packs
  __shared__ float    s_lv[NSB];
  __shared__ uint4    s_clist[8][NSB];     // per-wave compacted entries {bounds, lv, t, -}
  __shared__ int      s_nact[8];
  __shared__ float    s_acc[NE];           // per-block accumulator (LDS atomics)

  int tid = threadIdx.x;
  int ru = blockIdx.x;          // one row-unit per block
  int b = ru >> 8, r = ru & 255;

  for (int m = tid; m < NSB; m += 512) {
    int t = b + 2 * m;                     // steps of batch b only
    unsigned vld, fx, fy, sx, sy; float lv;
    step_params(t, pred, anc, &vld, &lv, &fx, &fy, &sx, &sy);
    if (!vld) { fx = 0xFFFFu; sx = 0xFFFFu; }   // lo=0xFFFF,hi=0 -> empty row range
    s_rxx[m] = make_uint2(fx, sx);
    s_cyy[m] = make_uint2(fy, sy);
    s_lv[m] = lv;
  }
  for (int e = tid; e < NE; e += 512) s_acc[e] = 0.0f;
  __syncthreads();

  int ln = tid & 63, w = tid >> 6;
  int win = w & 3, type = w >> 2;              // type: 0=F, 1=S
  int wlo = win * 64, whi = wlo + 64;
  int c = wlo + ln;

  // per-wave ordered compaction: steps whose TYPE-rect touches row r AND this col window;
  // list padded to a multiple of 4 with inert entries (empty bounds -> never "in").
  {
    int cnt = 0;
    #pragma unroll
    for (int g = 0; g < 3; ++g) {
      int m = g * 64 + ln;                 // m in [0,192)
      uint2 rx = s_rxx[m];
      uint2 cy = s_cyy[m];
      unsigned rb = type ? rx.y : rx.x;    // row bounds for this type
      unsigned cb = type ? cy.y : cy.x;    // col bounds for this type
      bool rowT = (r >= (int)(rb & 0xffffu)) && (r < (int)(rb >> 16));
      bool f = rowT && ((int)(cb & 0xffffu) < whi) && ((int)(cb >> 16) > wlo);
      unsigned long long msk = __ballot(f);
      int pos = (int)__popcll(msk & ((1ull << ln) - 1ull));
      if (f) s_clist[w][cnt + pos] =
          make_uint4(cb, __float_as_uint(s_lv[m]), (unsigned)(b + 2 * m), 0u);
      cnt += (int)__popcll(msk);
    }
    int pad = (4 - (cnt & 3)) & 3;
    if (ln < pad) s_clist[w][cnt + ln] = make_uint4(0xFFFFu, 0u, 0u, 0u);
    if (ln == 0) s_nact[w] = cnt + pad;
  }

  float dt = depth[(size_t)ru * IMGN + c];
  bool okp = dt >= 1.0f;
  float ldt = okp ? logf(dt) : 0.0f;
  int ce = okp ? c : 0x7fffffff;      // folds depth-mask into the column test
  __syncthreads();
  int nact = s_nact[w];

  // paint-state: lvP starts at ldt -> first paint and repaint share one formula:
  //   d1 = lv - lvP;  d2 = (lv-ldt)^2 - (lvP-ldt)^2 = d1*(lv + lvP - 2*ldt)
  // first-paint counts via SCALAR mask: m = ballot(in) & ~hmask.
  unsigned long long hmask = 0ull;
  float lvP = ldt;
  float ldt2 = 2.0f * ldt;
  int coff = type * 3;                // acc comps 0-2 (F) or 3-5 (S)
  for (int idx = 0; idx < nact; idx += 4) {
    uint4 E0 = s_clist[w][idx + 0];
    uint4 E1 = s_clist[w][idx + 1];
    uint4 E2 = s_clist[w][idx + 2];
    uint4 E3 = s_clist[w][idx + 3];
    bool in0 = (ce >= (int)(E0.x & 0xffffu)) && (ce < (int)(E0.x >> 16));
    bool in1 = (ce >= (int)(E1.x & 0xffffu)) && (ce < (int)(E1.x >> 16));
    bool in2 = (ce >= (int)(E2.x & 0xffffu)) && (ce < (int)(E2.x >> 16));
    bool in3 = (ce >= (int)(E3.x & 0xffffu)) && (ce < (int)(E3.x >> 16));
    unsigned long long a0 = __ballot(in0), a1 = __ballot(in1);
    unsigned long long a2 = __ballot(in2), a3 = __ballot(in3);
    if ((a0 | a1 | a2 | a3) == 0ull) continue;
    unsigned long long m0 = a0 & ~hmask; hmask |= a0;
    unsigned long long m1 = a1 & ~hmask; hmask |= a1;
    unsigned long long m2 = a2 & ~hmask; hmask |= a2;
    unsigned long long m3 = a3 & ~hmask; hmask |= a3;
    float lv0 = __uint_as_float(E0.y), lv1 = __uint_as_float(E1.y);
    float lv2 = __uint_as_float(E2.y), lv3 = __uint_as_float(E3.y);
    // sequential per-lane state updates (order matters)
    float d10 = in0 ? (lv0 - lvP) : 0.0f;
    float d20 = d10 * (lv0 + lvP - ldt2);
    lvP = in0 ? lv0 : lvP;
    float d11 = in1 ? (lv1 - lvP) : 0.0f;
    float d21 = d11 * (lv1 + lvP - ldt2);
    lvP = in1 ? lv1 : lvP;
    float d12 = in2 ? (lv2 - lvP) : 0.0f;
    float d22 = d12 * (lv2 + lvP - ldt2);
    lvP = in2 ? lv2 : lvP;
    float d13 = in3 ? (lv3 - lvP) : 0.0f;
    float d23 = d13 * (lv3 + lvP - ldt2);
    lvP = in3 ? lv3 : lvP;
    // 8 independent DPP chains interleave
    d10 = wsum_dpp(d10); d20 = wsum_dpp(d20);
    d11 = wsum_dpp(d11); d21 = wsum_dpp(d21);
    d12 = wsum_dpp(d12); d22 = wsum_dpp(d22);
    d13 = wsum_dpp(d13); d23 = wsum_dpp(d23);
    if (ln == 63) {
      float c0 = (float)__popcll(m0), c1 = (float)__popcll(m1);
      float c2 = (float)__popcll(m2), c3 = (float)__popcll(m3);
      float* b0 = s_acc + (int)E0.z * 6 + coff;
      if (c0  != 0.f) atomicAdd(b0 + 0, c0);
      if (d10 != 0.f) atomicAdd(b0 + 1, d10);
      if (d20 != 0.f) atomicAdd(b0 + 2, d20);
      float* b1 = s_acc + (int)E1.z * 6 + coff;
      if (c1  != 0.f) atomicAdd(b1 + 0, c1);
      if (d11 != 0.f) atomicAdd(b1 + 1, d11);
      if (d21 != 0.f) atomicAdd(b1 + 2, d21);
      float* b2 = s_acc + (int)E2.z * 6 + coff;
      if (c2  != 0.f) atomicAdd(b2 + 0, c2);
      if (d12 != 0.f) atomicAdd(b2 + 1, d12);
      if (d22 != 0.f) atomicAdd(b2 + 2, d22);
      float* b3 = s_acc + (int)E3.z * 6 + coff;
      if (c3  != 0.f) atomicAdd(b3 + 0, c3);
      if (d13 != 0.f) atomicAdd(b3 + 1, d13);
      if (d23 != 0.f) atomicAdd(b3 + 2, d23);
    }
  }
  __syncthreads();
  // contiguous coalesced write: 9216 B per block
  for (int e = tid; e < NE; e += 512)
    scratch[(size_t)blockIdx.x * NE + e] = s_acc[e];
}

// ---------------- Kernel R: parallel reduce over kB blocks (coalesced + unroll-8) ----------------
// grid = NRB=36 blocks x 256 threads. Block g owns e in [g*64, g*64+64);
// lane ln -> e = g*64+ln; wave w sums bk in [w*128, w*128+128) with 8 independent streams.
__global__ __launch_bounds__(256) void yolo_kR(const float* __restrict__ scratch,
                                               double* __restrict__ reduced){
  __shared__ double part[4][64];
  int ln = threadIdx.x & 63, w = threadIdx.x >> 6;
  int e = blockIdx.x * 64 + ln;
  const float* p = scratch + e;
  double s0 = 0, s1 = 0, s2 = 0, s3 = 0, s4 = 0, s5 = 0, s6 = 0, s7 = 0;
  int bk0 = w * (NB / 4);
  for (int bk = bk0; bk < bk0 + NB / 4; bk += 8) {
    s0 += (double)p[(size_t)(bk + 0) * NE];
    s1 += (double)p[(size_t)(bk + 1) * NE];
    s2 += (double)p[(size_t)(bk + 2) * NE];
    s3 += (double)p[(size_t)(bk + 3) * NE];
    s4 += (double)p[(size_t)(bk + 4) * NE];
    s5 += (double)p[(size_t)(bk + 5) * NE];
    s6 += (double)p[(size_t)(bk + 6) * NE];
    s7 += (double)p[(size_t)(bk + 7) * NE];
  }
  part[w][ln] = ((s0 + s1) + (s2 + s3)) + ((s4 + s5) + (s6 + s7));
  __syncthreads();
  if (w == 0)
    reduced[e] = part[0][ln] + part[1][ln] + part[2][ln] + part[3][ln];
}

// ---------------- Kernel C: YOLO losses + prefix over steps + final loss ----------------
__global__ __launch_bounds__(384) void yolo_kC(const float* __restrict__ pred,
                                               const float* __restrict__ tgt,
                                               const float* __restrict__ anc,
                                               const double* __restrict__ reduced,
                                               float* __restrict__ out){
  __shared__ double sd[NE];
  __shared__ double chunk[6 * 6];     // [chunkIdx][comp], chunks of 64 steps
  __shared__ double rl[6], rc[6];
  __shared__ float  ry[6 * 6];
  int tid = threadIdx.x;
  for (int e = tid; e < NE; e += 384) sd[e] = reduced[e];

  // ---- YOLO losses; cell order (b,a,i,j) ----
  float s_obj, s_bce, s_bcecnt, s_objls, s_boxls, s_clsls;
  {
    int t = tid;
    int j = t % SN;
    int i = (t / SN) % SN;
    int a = (t / (SN * SN)) % AN;
    int b = t / (SN * SN * AN);
    const float* pc = pred + (size_t)((((b * AN + a) * SN + i) * SN + j)) * PRED_C;
    const float* tc = tgt  + (size_t)((((b * AN + a) * SN + i) * SN + j)) * 6;
    float t0 = tc[0];
    float objf  = (t0 == 1.0f) ? 1.0f : 0.0f;
    float noobj = (t0 == 0.0f) ? 1.0f : 0.0f;
    float p0 = pc[0];
    float l = fmaxf(p0, 0.0f) - p0 * t0 + log1pf(expf(-fabsf(p0)));
    s_bce = l * noobj; s_bcecnt = noobj; s_obj = objf;
    float aw = anc[2 * a], ah = anc[2 * a + 1];
    float sxp = 1.0f / (1.0f + expf(-pc[1]));
    float syp = 1.0f / (1.0f + expf(-pc[2]));
    float bw = expf(pc[3]) * aw, bh = expf(pc[4]) * ah;
    float ax1 = sxp - bw * 0.5f, ax2 = sxp + bw * 0.5f;
    float ay1 = syp - bh * 0.5f, ay2 = syp + bh * 0.5f;
    float bx1 = tc[1] - tc[3] * 0.5f, bx2 = tc[1] + tc[3] * 0.5f;
    float by1 = tc[2] - tc[4] * 0.5f, by2 = tc[2] + tc[4] * 0.5f;
    float iw = fmaxf(fminf(ax2, bx2) - fmaxf(ax1, bx1), 0.0f);
    float ih = fmaxf(fminf(ay2, by2) - fmaxf(ay1, by1), 0.0f);
    float inter = iw * ih;
    float areaA = fabsf((ax2 - ax1) * (ay2 - ay1));
    float areaB = fabsf((bx2 - bx1) * (by2 - by1));
    float iou = inter / (areaA + areaB - inter + 1e-6f);
    float sp0 = 1.0f / (1.0f + expf(-p0));
    float od = sp0 - iou * t0;
    s_objls = od * od * objf;
    float dx = sxp - tc[1], dy = syp - tc[2];
    float dw = pc[3] - logf(1e-16f + tc[3] / aw);
    float dh = pc[4] - logf(1e-16f + tc[4] / ah);
    s_boxls = (dx * dx + dy * dy + dw * dw + dh * dh) * objf;
    int lbl = (int)tc[5];
    float mx = -INFINITY;
    for (int c = 0; c < CN; ++c) mx = fmaxf(mx, pc[6 + c]);
    float se = 0.0f;
    for (int c = 0; c < CN; ++c) se += expf(pc[6 + c] - mx);
    float nll = mx + logf(se) - pc[6 + lbl];
    s_clsls = nll * objf;
  }
  {
    int wv = tid >> 6, ln = tid & 63;
    float vals[6] = { s_obj, s_bce, s_bcecnt, s_objls, s_boxls, s_clsls };
    #pragma unroll
    for (int ci = 0; ci < 6; ++ci) {
      float v = wredf(vals[ci]);
      if (ln == 0) ry[ci * 6 + wv] = v;
    }
  }

  // ---- valid bit for step tid (recomputed; only w/h chain matters) ----
  unsigned vld, ufx, ufy, usx, usy; float ulv;
  step_params(tid, pred, anc, &vld, &ulv, &ufx, &ufy, &usx, &usy);

  __syncthreads();
  // chunk sums: wave ch reduces chunk ch (64 steps) for all 6 comps in parallel
  {
    int ch = tid >> 6, ln = tid & 63;
    #pragma unroll
    for (int comp = 0; comp < 6; ++comp) {
      double v = wredd(sd[(ch * 64 + ln) * 6 + comp]);
      if (ln == 0) chunk[ch * 6 + comp] = v;
    }
  }
  __syncthreads();

  int t = tid;
  int ch = t >> 6;
  double P[6];
  #pragma unroll
  for (int comp = 0; comp < 6; ++comp) {
    double s = 0.0;
    for (int cc = 0; cc < ch; ++cc) s += chunk[cc * 6 + comp];
    for (int tt = (ch << 6); tt <= t; ++tt) s += sd[tt * 6 + comp];
    P[comp] = s;   // inclusive prefix: sums AFTER step t's paint
  }
  double lossd = 0.0, cntd = 0.0;
  {
    double n = P[0], Sg = P[1], Sg2 = P[2];
    double mean = Sg / fmax(n, 1.0);
    double var = (Sg2 - 2.0 * mean * Sg + n * mean * mean) / fmax(n - 1.0, 1.0);
    double Dg = var + 0.15 * mean * mean;
    double pl = 10.0 * sqrt(fmax(Dg, 1e-30));
    if (vld && n >= 2.0) { lossd += pl; cntd += 1.0; }
  }
  {
    double n = P[3], Sg = P[4], Sg2 = P[5];
    double mean = Sg / fmax(n, 1.0);
    double var = (Sg2 - 2.0 * mean * Sg + n * mean * mean) / fmax(n - 1.0, 1.0);
    double Dg = var + 0.15 * mean * mean;
    double pl = 10.0 * sqrt(fmax(Dg, 1e-30));
    if (vld && n >= 2.0) { lossd += pl; cntd += 1.0; }
  }
  int wv = tid >> 6, ln = tid & 63;
  double L = wredd(lossd), C = wredd(cntd);
  if (ln == 0) { rl[wv] = L; rc[wv] = C; }
  __syncthreads();
  if (tid == 0) {
    double totL = 0.0, totC = 0.0;
    for (int i = 0; i < 6; ++i) { totL += rl[i]; totC += rc[i]; }
    float yolo[6];
    #pragma unroll
    for (int ci = 0; ci < 6; ++ci) {
      float s = 0.0f;
      for (int w2 = 0; w2 < 6; ++w2) s += ry[ci * 6 + w2];
      yolo[ci] = s;
    }
    float dl = (float)(totL / fmax(totC, 1.0));
    float nobj = fmaxf(yolo[0], 1.0f);
    float noo  = yolo[1] / fmaxf(yolo[2], 1.0f);
    float objl = yolo[3] / nobj;
    float boxl = yolo[4] / (nobj * 4.0f);
    float clsl = yolo[5] / nobj;
    out[0] = 10.0f * boxl + objl + 10.0f * noo + clsl + dl;
  }
}

extern "C" void kernel_launch(void* const* d_in, const int* in_sizes, int n_in,
                              void* d_out, int out_size, void* d_ws, size_t ws_size,
                              hipStream_t stream) {
  const float* pred  = (const float*)d_in[0];
  const float* tgt   = (const float*)d_in[1];
  const float* anc   = (const float*)d_in[2];
  const float* depth = (const float*)d_in[3];

  float*  scratch = (float*)d_ws;                                          // NB*NE floats = 4.72 MB
  double* reduced = (double*)((char*)d_ws + (size_t)NB * NE * sizeof(float));   // NE doubles

  hipLaunchKernelGGL(yolo_kB, dim3(NB), dim3(512), 0, stream, pred, anc, depth, scratch);
  hipLaunchKernelGGL(yolo_kR, dim3(NRB), dim3(256), 0, stream, scratch, reduced);
  hipLaunchKernelGGL(yolo_kC, dim3(1), dim3(384), 0, stream, pred, tgt, anc, reduced, (float*)d_out);
}